// Round 1
// baseline (271.950 us; speedup 1.0000x reference)
//
#include <hip/hip_runtime.h>
#include <hip/hip_bf16.h>
#include <stdint.h>

#define BB 16
#define NN 4096
#define MM 1024
#define C1 128
#define C2 256
#define CIN 384
#define CO 256
#define ROWS (BB * NN)

typedef __attribute__((ext_vector_type(8))) short bf16x8;
typedef __attribute__((ext_vector_type(4))) float f32x4;

__device__ inline float u2f(uint32_t u) { union { uint32_t u; float f; } v; v.u = u; return v.f; }
__device__ inline uint32_t f2u(float f) { union { float f; uint32_t u; } v; v.f = f; return v.u; }
// round-to-nearest-even f32 -> bf16
__device__ inline unsigned short f2bf(float f) {
  uint32_t u = f2u(f);
  uint32_t r = u + 0x7fffu + ((u >> 16) & 1u);
  return (unsigned short)(r >> 16);
}
__device__ inline float bflo(uint32_t w) { return u2f(w << 16); }
__device__ inline float bfhi(uint32_t w) { return u2f(w & 0xffff0000u); }

// ---------------------------------------------------------------- three_nn
__global__ __launch_bounds__(256) void nn_kernel(const float* __restrict__ xyz1,
                                                 const float* __restrict__ xyz2,
                                                 int* __restrict__ idx,
                                                 float* __restrict__ wgt) {
  __shared__ float4 q[MM];  // 16 KB
  int b = blockIdx.x >> 4;                   // 16 blocks per batch (N/256)
  int n = ((blockIdx.x & 15) << 8) + threadIdx.x;
  const float* x2 = xyz2 + (size_t)b * MM * 3;
  for (int j = threadIdx.x; j < MM; j += 256)
    q[j] = make_float4(x2[j * 3 + 0], x2[j * 3 + 1], x2[j * 3 + 2], 0.f);
  __syncthreads();
  const float* p = xyz1 + ((size_t)b * NN + n) * 3;
  float px = p[0], py = p[1], pz = p[2];
  float d0 = 1e30f, d1 = 1e30f, d2 = 1e30f;
  int i0 = 0, i1 = 0, i2 = 0;
#pragma unroll 4
  for (int j = 0; j < MM; ++j) {
    float4 qv = q[j];
    float dx = px - qv.x, dy = py - qv.y, dz = pz - qv.z;
    float d = dx * dx + dy * dy + dz * dz;
    if (d < d2) {
      if (d < d0)      { d2 = d1; i2 = i1; d1 = d0; i1 = i0; d0 = d; i0 = j; }
      else if (d < d1) { d2 = d1; i2 = i1; d1 = d;  i1 = j; }
      else             { d2 = d;  i2 = j; }
    }
  }
  float e0 = fmaxf(d0, 1e-10f), e1 = fmaxf(d1, 1e-10f), e2 = fmaxf(d2, 1e-10f);
  float v0 = 1.f / e0, v1 = 1.f / e1, v2 = 1.f / e2;
  float inv = 1.f / (v0 + v1 + v2);
  size_t base = ((size_t)b * NN + n) * 3;
  idx[base + 0] = i0; idx[base + 1] = i1; idx[base + 2] = i2;
  wgt[base + 0] = v0 * inv; wgt[base + 1] = v1 * inv; wgt[base + 2] = v2 * inv;
}

// -------------------------------------------- interpolate + concat -> x bf16
__global__ __launch_bounds__(256) void interp_kernel(const float* __restrict__ points2,
                                                     const float* __restrict__ points1,
                                                     const int* __restrict__ idx,
                                                     const float* __restrict__ wgt,
                                                     unsigned short* __restrict__ X) {
  int row = blockIdx.x * 2 + (threadIdx.x >> 7);
  int t = threadIdx.x & 127;
  int b = row >> 12;  // N = 4096 rows per batch
  unsigned short* xr = X + (size_t)row * CIN;
  if (t < 64) {
    const int* id = idx + (size_t)row * 3;
    const float* w = wgt + (size_t)row * 3;
    const float* p2 = points2 + (size_t)b * MM * C2 + t * 4;
    float w0 = w[0], w1 = w[1], w2 = w[2];
    float4 a0 = *(const float4*)(p2 + (size_t)id[0] * C2);
    float4 a1 = *(const float4*)(p2 + (size_t)id[1] * C2);
    float4 a2 = *(const float4*)(p2 + (size_t)id[2] * C2);
    ushort4 o;
    o.x = f2bf(w0 * a0.x + w1 * a1.x + w2 * a2.x);
    o.y = f2bf(w0 * a0.y + w1 * a1.y + w2 * a2.y);
    o.z = f2bf(w0 * a0.z + w1 * a1.z + w2 * a2.z);
    o.w = f2bf(w0 * a0.w + w1 * a1.w + w2 * a2.w);
    *(ushort4*)(xr + t * 4) = o;
  } else if (t < 96) {
    int c = (t - 64) * 4;
    float4 a = *(const float4*)(points1 + (size_t)row * C1 + c);
    ushort4 o;
    o.x = f2bf(a.x); o.y = f2bf(a.y); o.z = f2bf(a.z); o.w = f2bf(a.w);
    *(ushort4*)(xr + C2 + c) = o;
  }
}

// ------------------------------------- weight convert + transpose: Wt[n][k]
__global__ __launch_bounds__(256) void wt_kernel(const float* __restrict__ W,
                                                 unsigned short* __restrict__ Wt,
                                                 int K, int Nc) {
  int i = blockIdx.x * 256 + threadIdx.x;
  if (i >= K * Nc) return;
  int n = i / K, k = i - n * K;
  Wt[i] = f2bf(W[(size_t)k * Nc + n]);
}

// ---------------------------------------------------------------- bf16 GEMM
// C[m][n] = sum_k A[m][k] * Bt[n][k];  A:[Mr][K] bf16, Bt:[Nc][K] bf16
__device__ inline void gload_lds16(const void* g, void* l) {
  __builtin_amdgcn_global_load_lds(
      (const __attribute__((address_space(1))) void*)g,
      (__attribute__((address_space(3))) void*)l, 16, 0, 0);
}

__global__ __launch_bounds__(256) void gemm_nt(const unsigned short* __restrict__ A,
                                               const unsigned short* __restrict__ Bt,
                                               unsigned short* __restrict__ C,
                                               int K, int Nc) {
  __shared__ unsigned short lA[128 * 64];  // [128 m][64 k]
  __shared__ unsigned short lB[128 * 64];  // [128 n][64 k]
  int t = threadIdx.x;
  int lane = t & 63, wave = t >> 6;
  int wr = wave >> 1, wc = wave & 1;
  int m0 = blockIdx.x * 128, n0 = blockIdx.y * 128;
  int lrow = lane >> 3, lcol = (lane & 7) * 8;
  f32x4 acc[4][4] = {};
  for (int k0 = 0; k0 < K; k0 += 64) {
#pragma unroll
    for (int i = 0; i < 4; ++i) {
      int row = i * 32 + wave * 8 + lrow;
      gload_lds16(A + (size_t)(m0 + row) * K + k0 + lcol, &lA[i * 2048 + wave * 512]);
    }
#pragma unroll
    for (int i = 0; i < 4; ++i) {
      int row = i * 32 + wave * 8 + lrow;
      gload_lds16(Bt + (size_t)(n0 + row) * K + k0 + lcol, &lB[i * 2048 + wave * 512]);
    }
    __syncthreads();
#pragma unroll
    for (int kk = 0; kk < 2; ++kk) {
      int ko = kk * 32 + (lane >> 4) * 8;
      bf16x8 af[4], bfr[4];
#pragma unroll
      for (int m = 0; m < 4; ++m)
        af[m] = *(const bf16x8*)&lA[(wr * 64 + m * 16 + (lane & 15)) * 64 + ko];
#pragma unroll
      for (int n2 = 0; n2 < 4; ++n2)
        bfr[n2] = *(const bf16x8*)&lB[(wc * 64 + n2 * 16 + (lane & 15)) * 64 + ko];
#pragma unroll
      for (int m = 0; m < 4; ++m)
#pragma unroll
        for (int n2 = 0; n2 < 4; ++n2)
          acc[m][n2] = __builtin_amdgcn_mfma_f32_16x16x32_bf16(af[m], bfr[n2], acc[m][n2], 0, 0, 0);
    }
    __syncthreads();
  }
  int crow0 = m0 + wr * 64 + (lane >> 4) * 4;
  int ccol0 = n0 + wc * 64 + (lane & 15);
#pragma unroll
  for (int m = 0; m < 4; ++m)
#pragma unroll
    for (int n2 = 0; n2 < 4; ++n2) {
      size_t rb = (size_t)(crow0 + m * 16);
      int cc = ccol0 + n2 * 16;
#pragma unroll
      for (int j = 0; j < 4; ++j)
        C[(rb + j) * Nc + cc] = f2bf(acc[m][n2][j]);
    }
}

// ----------------------------------------------------- per-channel sum/sumsq
__global__ __launch_bounds__(256) void stats_kernel(const unsigned short* __restrict__ Y,
                                                    float* __restrict__ stats) {
  __shared__ float sh[512];
  int t = threadIdx.x;
  sh[t] = 0.f; sh[t + 256] = 0.f;
  __syncthreads();
  int colg = (t & 31) * 8;
  int rowo = t >> 5;
  size_t r0 = (size_t)blockIdx.x * 256;
  float s[8] = {}, ss[8] = {};
  for (int r = rowo; r < 256; r += 8) {
    uint4 v = *(const uint4*)(Y + (r0 + r) * 256 + colg);
    uint32_t wv[4] = {v.x, v.y, v.z, v.w};
#pragma unroll
    for (int q = 0; q < 4; ++q) {
      float f0 = bflo(wv[q]), f1 = bfhi(wv[q]);
      s[2 * q] += f0;     ss[2 * q] += f0 * f0;
      s[2 * q + 1] += f1; ss[2 * q + 1] += f1 * f1;
    }
  }
#pragma unroll
  for (int q = 0; q < 8; ++q) {
    atomicAdd(&sh[colg + q], s[q]);
    atomicAdd(&sh[256 + colg + q], ss[q]);
  }
  __syncthreads();
  atomicAdd(&stats[t], sh[t]);
  atomicAdd(&stats[256 + t], sh[256 + t]);
}

__global__ void finalize_kernel(const float* __restrict__ stats, const float* __restrict__ g,
                                const float* __restrict__ be, float* __restrict__ scsh) {
  int c = threadIdx.x;
  float mean = stats[c] * (1.f / ROWS);
  float var = stats[256 + c] * (1.f / ROWS) - mean * mean;
  float sc = g[c] * rsqrtf(var + 1e-3f);
  scsh[c] = sc;
  scsh[256 + c] = be[c] - mean * sc;
}

// ----------------------------------------- BN+ReLU apply, bf16 in-place
__global__ __launch_bounds__(256) void apply_bf16(unsigned short* __restrict__ Y,
                                                  const float* __restrict__ scsh) {
  __shared__ float sc[256], sh[256];
  int t = threadIdx.x;
  sc[t] = scsh[t]; sh[t] = scsh[256 + t];
  __syncthreads();
  size_t base = ((size_t)blockIdx.x * 256 + t) * 8;
  int c0 = (int)(base & 255);
  uint4 v = *(const uint4*)(Y + base);
  uint32_t wv[4] = {v.x, v.y, v.z, v.w};
  uint32_t ov[4];
#pragma unroll
  for (int q = 0; q < 4; ++q) {
    float f0 = fmaxf(bflo(wv[q]) * sc[c0 + 2 * q] + sh[c0 + 2 * q], 0.f);
    float f1 = fmaxf(bfhi(wv[q]) * sc[c0 + 2 * q + 1] + sh[c0 + 2 * q + 1], 0.f);
    ov[q] = (uint32_t)f2bf(f0) | ((uint32_t)f2bf(f1) << 16);
  }
  uint4 o; o.x = ov[0]; o.y = ov[1]; o.z = ov[2]; o.w = ov[3];
  *(uint4*)(Y + base) = o;
}

// ----------------------------------------- BN+ReLU apply, fp32 out
__global__ __launch_bounds__(256) void apply_f32(const unsigned short* __restrict__ Y,
                                                 const float* __restrict__ scsh,
                                                 float* __restrict__ out) {
  __shared__ float sc[256], sh[256];
  int t = threadIdx.x;
  sc[t] = scsh[t]; sh[t] = scsh[256 + t];
  __syncthreads();
  size_t base = ((size_t)blockIdx.x * 256 + t) * 8;
  int c0 = (int)(base & 255);
  uint4 v = *(const uint4*)(Y + base);
  uint32_t wv[4] = {v.x, v.y, v.z, v.w};
  float o[8];
#pragma unroll
  for (int q = 0; q < 4; ++q) {
    o[2 * q]     = fmaxf(bflo(wv[q]) * sc[c0 + 2 * q] + sh[c0 + 2 * q], 0.f);
    o[2 * q + 1] = fmaxf(bfhi(wv[q]) * sc[c0 + 2 * q + 1] + sh[c0 + 2 * q + 1], 0.f);
  }
  *(float4*)(out + base) = make_float4(o[0], o[1], o[2], o[3]);
  *(float4*)(out + base + 4) = make_float4(o[4], o[5], o[6], o[7]);
}

extern "C" void kernel_launch(void* const* d_in, const int* in_sizes, int n_in,
                              void* d_out, int out_size, void* d_ws, size_t ws_size,
                              hipStream_t stream) {
  const float* xyz1    = (const float*)d_in[0];
  const float* xyz2    = (const float*)d_in[1];
  const float* points1 = (const float*)d_in[2];
  const float* points2 = (const float*)d_in[3];
  const float* W0      = (const float*)d_in[4];
  const float* g0      = (const float*)d_in[6];
  const float* be0     = (const float*)d_in[7];
  const float* W1      = (const float*)d_in[8];
  const float* g1      = (const float*)d_in[10];
  const float* be1     = (const float*)d_in[11];
  float* out = (float*)d_out;

  // workspace layout (bytes)
  char* ws = (char*)d_ws;
  unsigned short* X   = (unsigned short*)(ws);                       // ROWS*384 bf16 (reused for Y2)
  unsigned short* Y1  = (unsigned short*)(ws + 50331648);            // ROWS*256 bf16
  unsigned short* W0t = (unsigned short*)(ws + 50331648 + 33554432); // 384*256 bf16 (transposed)
  unsigned short* W1t = (unsigned short*)(ws + 50331648 + 33554432 + 196608);
  float* stats = (float*)(ws + 50331648 + 33554432 + 196608 + 131072); // 1024 f32 (two BN stat sets)
  float* scsh  = stats + 1024;                                        // 1024 f32 (two scale/shift sets)
  int*   idx   = (int*)(scsh + 1024);                                 // ROWS*3
  float* wgt   = (float*)(idx + ROWS * 3);                            // ROWS*3
  unsigned short* Y2 = X;  // x buffer free after gemm1

  hipMemsetAsync(stats, 0, 1024 * sizeof(float), stream);

  wt_kernel<<<(CIN * CO + 255) / 256, 256, 0, stream>>>(W0, W0t, CIN, CO);
  wt_kernel<<<(CO * CO + 255) / 256, 256, 0, stream>>>(W1, W1t, CO, CO);

  nn_kernel<<<BB * (NN / 256), 256, 0, stream>>>(xyz1, xyz2, idx, wgt);
  interp_kernel<<<ROWS / 2, 256, 0, stream>>>(points2, points1, idx, wgt, X);

  dim3 gg(ROWS / 128, 2);
  gemm_nt<<<gg, 256, 0, stream>>>(X, W0t, Y1, CIN, CO);
  stats_kernel<<<ROWS / 256, 256, 0, stream>>>(Y1, stats);
  finalize_kernel<<<1, 256, 0, stream>>>(stats, g0, be0, scsh);
  apply_bf16<<<(size_t)ROWS * CO / (256 * 8), 256, 0, stream>>>(Y1, scsh);

  gemm_nt<<<gg, 256, 0, stream>>>(Y1, W1t, Y2, CO, CO);
  stats_kernel<<<ROWS / 256, 256, 0, stream>>>(Y2, stats + 512);
  finalize_kernel<<<1, 256, 0, stream>>>(stats + 512, g1, be1, scsh + 512);
  apply_f32<<<(size_t)ROWS * CO / (256 * 8), 256, 0, stream>>>(Y2, scsh + 512, out);
}

// Round 2
// 202.690 us; speedup vs baseline: 1.3417x; 1.3417x over previous
//
#include <hip/hip_runtime.h>
#include <hip/hip_bf16.h>
#include <stdint.h>

#define BB 16
#define NN 4096
#define MM 1024
#define C1 128
#define C2 256
#define CIN 384
#define CO 256
#define ROWS (BB * NN)

typedef __attribute__((ext_vector_type(8))) short bf16x8;
typedef __attribute__((ext_vector_type(4))) float f32x4;

__device__ inline float u2f(uint32_t u) { union { uint32_t u; float f; } v; v.u = u; return v.f; }
__device__ inline uint32_t f2u(float f) { union { float f; uint32_t u; } v; v.f = f; return v.u; }
// round-to-nearest-even f32 -> bf16
__device__ inline unsigned short f2bf(float f) {
  uint32_t u = f2u(f);
  uint32_t r = u + 0x7fffu + ((u >> 16) & 1u);
  return (unsigned short)(r >> 16);
}
__device__ inline float bflo(uint32_t w) { return u2f(w << 16); }
__device__ inline float bfhi(uint32_t w) { return u2f(w & 0xffff0000u); }

// ---------------------------------------------------------------- three_nn
// 8 threads per query; each scans j === tq (mod 8); branchless sorted top-3
// insert; shfl_xor merge. Distance formula identical to reference (diff^2 sum)
// so selection matches np ref (selection mismatch would cost ~0.3 absmax).
#define NN_INS(dd, jj_)                                        \
  {                                                            \
    bool c0 = (dd) < e0, c1 = (dd) < e1, c2 = (dd) < e2;       \
    e2 = c2 ? (c1 ? e1 : (dd)) : e2;                           \
    i2 = c2 ? (c1 ? i1 : (jj_)) : i2;                          \
    e1 = c1 ? (c0 ? e0 : (dd)) : e1;                           \
    i1 = c1 ? (c0 ? i0 : (jj_)) : i1;                          \
    e0 = c0 ? (dd) : e0;                                       \
    i0 = c0 ? (jj_) : i0;                                      \
  }

__global__ __launch_bounds__(256) void nn_kernel(const float* __restrict__ xyz1,
                                                 const float* __restrict__ xyz2,
                                                 int* __restrict__ idx,
                                                 float* __restrict__ wgt) {
  __shared__ float4 q[MM];  // 16 KB
  int b = blockIdx.x >> 7;                 // 128 blocks per batch (N/32)
  int qbase = (blockIdx.x & 127) << 5;     // 32 queries per block
  const float* x2 = xyz2 + (size_t)b * MM * 3;
  for (int j = threadIdx.x; j < MM; j += 256)
    q[j] = make_float4(x2[j * 3 + 0], x2[j * 3 + 1], x2[j * 3 + 2], 0.f);
  __syncthreads();
  int n = qbase + (threadIdx.x >> 3);
  int tq = threadIdx.x & 7;
  const float* p = xyz1 + ((size_t)b * NN + n) * 3;
  float px = p[0], py = p[1], pz = p[2];
  float e0 = 1e30f, e1 = 1e30f, e2 = 1e30f;
  int i0 = 0, i1 = 0, i2 = 0;
#pragma unroll 8
  for (int jj = 0; jj < MM / 8; ++jj) {
    int j = jj * 8 + tq;
    float4 qv = q[j];
    float dx = px - qv.x, dy = py - qv.y, dz = pz - qv.z;
    float d = dx * dx + dy * dy + dz * dz;
    NN_INS(d, j);
  }
  // merge the 8 partial top-3 sets (lanes tq=0..7 of each 8-lane group)
#pragma unroll
  for (int mk = 1; mk <= 4; mk <<= 1) {
    float f0 = __shfl_xor(e0, mk), f1 = __shfl_xor(e1, mk), f2 = __shfl_xor(e2, mk);
    int j0 = __shfl_xor(i0, mk), j1 = __shfl_xor(i1, mk), j2 = __shfl_xor(i2, mk);
    NN_INS(f0, j0);
    NN_INS(f1, j1);
    NN_INS(f2, j2);
  }
  if (tq == 0) {
    float a0 = fmaxf(e0, 1e-10f), a1 = fmaxf(e1, 1e-10f), a2 = fmaxf(e2, 1e-10f);
    float v0 = 1.f / a0, v1 = 1.f / a1, v2 = 1.f / a2;
    float inv = 1.f / (v0 + v1 + v2);
    size_t base = ((size_t)b * NN + n) * 3;
    idx[base + 0] = i0; idx[base + 1] = i1; idx[base + 2] = i2;
    wgt[base + 0] = v0 * inv; wgt[base + 1] = v1 * inv; wgt[base + 2] = v2 * inv;
  }
}

// -------------------------------------------- interpolate + concat -> x bf16
__global__ __launch_bounds__(256) void interp_kernel(const float* __restrict__ points2,
                                                     const float* __restrict__ points1,
                                                     const int* __restrict__ idx,
                                                     const float* __restrict__ wgt,
                                                     unsigned short* __restrict__ X) {
  int row = blockIdx.x * 2 + (threadIdx.x >> 7);
  int t = threadIdx.x & 127;
  int b = row >> 12;  // N = 4096 rows per batch
  unsigned short* xr = X + (size_t)row * CIN;
  if (t < 64) {
    const int* id = idx + (size_t)row * 3;
    const float* w = wgt + (size_t)row * 3;
    const float* p2 = points2 + (size_t)b * MM * C2 + t * 4;
    float w0 = w[0], w1 = w[1], w2 = w[2];
    float4 a0 = *(const float4*)(p2 + (size_t)id[0] * C2);
    float4 a1 = *(const float4*)(p2 + (size_t)id[1] * C2);
    float4 a2 = *(const float4*)(p2 + (size_t)id[2] * C2);
    ushort4 o;
    o.x = f2bf(w0 * a0.x + w1 * a1.x + w2 * a2.x);
    o.y = f2bf(w0 * a0.y + w1 * a1.y + w2 * a2.y);
    o.z = f2bf(w0 * a0.z + w1 * a1.z + w2 * a2.z);
    o.w = f2bf(w0 * a0.w + w1 * a1.w + w2 * a2.w);
    *(ushort4*)(xr + t * 4) = o;
  } else if (t < 96) {
    int c = (t - 64) * 4;
    float4 a = *(const float4*)(points1 + (size_t)row * C1 + c);
    ushort4 o;
    o.x = f2bf(a.x); o.y = f2bf(a.y); o.z = f2bf(a.z); o.w = f2bf(a.w);
    *(ushort4*)(xr + C2 + c) = o;
  }
}

// ------------------------------------- weight convert + transpose: Wt[n][k]
__global__ __launch_bounds__(256) void wt_kernel(const float* __restrict__ W,
                                                 unsigned short* __restrict__ Wt,
                                                 int K, int Nc) {
  int i = blockIdx.x * 256 + threadIdx.x;
  if (i >= K * Nc) return;
  int n = i / K, k = i - n * K;
  Wt[i] = f2bf(W[(size_t)k * Nc + n]);
}

// ---------------------------------------------------------------- bf16 GEMM
// C[m][n] = sum_k A[m][k] * Bt[n][k];  A:[Mr][K] bf16, Bt:[Nc][K] bf16
// Fused epilogue: per-channel sum / sumsq of the f32 accumulators -> stats.
__device__ inline void gload_lds16(const void* g, void* l) {
  __builtin_amdgcn_global_load_lds(
      (const __attribute__((address_space(1))) void*)g,
      (__attribute__((address_space(3))) void*)l, 16, 0, 0);
}

__global__ __launch_bounds__(256) void gemm_nt(const unsigned short* __restrict__ A,
                                               const unsigned short* __restrict__ Bt,
                                               unsigned short* __restrict__ C,
                                               float* __restrict__ stats,
                                               int K, int Nc) {
  __shared__ unsigned short lA[128 * 64];  // [128 m][64 k]
  __shared__ unsigned short lB[128 * 64];  // [128 n][64 k]
  __shared__ float sdat[256];              // 128 col sums + 128 col sumsq
  int t = threadIdx.x;
  int lane = t & 63, wave = t >> 6;
  int wr = wave >> 1, wc = wave & 1;
  int m0 = blockIdx.x * 128, n0 = blockIdx.y * 128;
  int lrow = lane >> 3, lcol = (lane & 7) * 8;
  if (t < 256) sdat[t] = 0.f;
  f32x4 acc[4][4] = {};
  for (int k0 = 0; k0 < K; k0 += 64) {
#pragma unroll
    for (int i = 0; i < 4; ++i) {
      int row = i * 32 + wave * 8 + lrow;
      gload_lds16(A + (size_t)(m0 + row) * K + k0 + lcol, &lA[i * 2048 + wave * 512]);
    }
#pragma unroll
    for (int i = 0; i < 4; ++i) {
      int row = i * 32 + wave * 8 + lrow;
      gload_lds16(Bt + (size_t)(n0 + row) * K + k0 + lcol, &lB[i * 2048 + wave * 512]);
    }
    __syncthreads();
#pragma unroll
    for (int kk = 0; kk < 2; ++kk) {
      int ko = kk * 32 + (lane >> 4) * 8;
      bf16x8 af[4], bfr[4];
#pragma unroll
      for (int m = 0; m < 4; ++m)
        af[m] = *(const bf16x8*)&lA[(wr * 64 + m * 16 + (lane & 15)) * 64 + ko];
#pragma unroll
      for (int n2 = 0; n2 < 4; ++n2)
        bfr[n2] = *(const bf16x8*)&lB[(wc * 64 + n2 * 16 + (lane & 15)) * 64 + ko];
#pragma unroll
      for (int m = 0; m < 4; ++m)
#pragma unroll
        for (int n2 = 0; n2 < 4; ++n2)
          acc[m][n2] = __builtin_amdgcn_mfma_f32_16x16x32_bf16(af[m], bfr[n2], acc[m][n2], 0, 0, 0);
    }
    __syncthreads();
  }
  // ---- C write (bf16) ----
  int crow0 = m0 + wr * 64 + (lane >> 4) * 4;
  int ccol0 = n0 + wc * 64 + (lane & 15);
#pragma unroll
  for (int m = 0; m < 4; ++m)
#pragma unroll
    for (int n2 = 0; n2 < 4; ++n2) {
      size_t rb = (size_t)(crow0 + m * 16);
      int cc = ccol0 + n2 * 16;
#pragma unroll
      for (int j = 0; j < 4; ++j)
        C[(rb + j) * Nc + cc] = f2bf(acc[m][n2][j]);
    }
  // ---- fused BN stats ----
  float s4[4] = {0.f, 0.f, 0.f, 0.f}, q4[4] = {0.f, 0.f, 0.f, 0.f};
#pragma unroll
  for (int m = 0; m < 4; ++m)
#pragma unroll
    for (int n2 = 0; n2 < 4; ++n2)
#pragma unroll
      for (int j = 0; j < 4; ++j) {
        float v = acc[m][n2][j];
        s4[n2] += v;
        q4[n2] += v * v;
      }
#pragma unroll
  for (int n2 = 0; n2 < 4; ++n2) {
    s4[n2] += __shfl_xor(s4[n2], 16);
    q4[n2] += __shfl_xor(q4[n2], 16);
    s4[n2] += __shfl_xor(s4[n2], 32);
    q4[n2] += __shfl_xor(q4[n2], 32);
  }
  if (lane < 16) {
#pragma unroll
    for (int n2 = 0; n2 < 4; ++n2) {
      int cl = wc * 64 + (lane & 15) + n2 * 16;  // local col 0..127
      atomicAdd(&sdat[cl], s4[n2]);
      atomicAdd(&sdat[128 + cl], q4[n2]);
    }
  }
  __syncthreads();
  if (t < 128) {
    atomicAdd(&stats[n0 + t], sdat[t]);
    atomicAdd(&stats[256 + n0 + t], sdat[128 + t]);
  }
}

__global__ void finalize_kernel(const float* __restrict__ stats, const float* __restrict__ g,
                                const float* __restrict__ be, float* __restrict__ scsh) {
  int c = threadIdx.x;
  float mean = stats[c] * (1.f / ROWS);
  float var = stats[256 + c] * (1.f / ROWS) - mean * mean;
  float sc = g[c] * rsqrtf(var + 1e-3f);
  scsh[c] = sc;
  scsh[256 + c] = be[c] - mean * sc;
}

// ----------------------------------------- BN+ReLU apply, bf16 in-place
__global__ __launch_bounds__(256) void apply_bf16(unsigned short* __restrict__ Y,
                                                  const float* __restrict__ scsh) {
  __shared__ float sc[256], sh[256];
  int t = threadIdx.x;
  sc[t] = scsh[t]; sh[t] = scsh[256 + t];
  __syncthreads();
  size_t base = ((size_t)blockIdx.x * 256 + t) * 8;
  int c0 = (int)(base & 255);
  uint4 v = *(const uint4*)(Y + base);
  uint32_t wv[4] = {v.x, v.y, v.z, v.w};
  uint32_t ov[4];
#pragma unroll
  for (int q = 0; q < 4; ++q) {
    float f0 = fmaxf(bflo(wv[q]) * sc[c0 + 2 * q] + sh[c0 + 2 * q], 0.f);
    float f1 = fmaxf(bfhi(wv[q]) * sc[c0 + 2 * q + 1] + sh[c0 + 2 * q + 1], 0.f);
    ov[q] = (uint32_t)f2bf(f0) | ((uint32_t)f2bf(f1) << 16);
  }
  uint4 o; o.x = ov[0]; o.y = ov[1]; o.z = ov[2]; o.w = ov[3];
  *(uint4*)(Y + base) = o;
}

// ----------------------------------------- BN+ReLU apply, fp32 out
__global__ __launch_bounds__(256) void apply_f32(const unsigned short* __restrict__ Y,
                                                 const float* __restrict__ scsh,
                                                 float* __restrict__ out) {
  __shared__ float sc[256], sh[256];
  int t = threadIdx.x;
  sc[t] = scsh[t]; sh[t] = scsh[256 + t];
  __syncthreads();
  size_t base = ((size_t)blockIdx.x * 256 + t) * 8;
  int c0 = (int)(base & 255);
  uint4 v = *(const uint4*)(Y + base);
  uint32_t wv[4] = {v.x, v.y, v.z, v.w};
  float o[8];
#pragma unroll
  for (int q = 0; q < 4; ++q) {
    o[2 * q]     = fmaxf(bflo(wv[q]) * sc[c0 + 2 * q] + sh[c0 + 2 * q], 0.f);
    o[2 * q + 1] = fmaxf(bfhi(wv[q]) * sc[c0 + 2 * q + 1] + sh[c0 + 2 * q + 1], 0.f);
  }
  *(float4*)(out + base) = make_float4(o[0], o[1], o[2], o[3]);
  *(float4*)(out + base + 4) = make_float4(o[4], o[5], o[6], o[7]);
}

extern "C" void kernel_launch(void* const* d_in, const int* in_sizes, int n_in,
                              void* d_out, int out_size, void* d_ws, size_t ws_size,
                              hipStream_t stream) {
  const float* xyz1    = (const float*)d_in[0];
  const float* xyz2    = (const float*)d_in[1];
  const float* points1 = (const float*)d_in[2];
  const float* points2 = (const float*)d_in[3];
  const float* W0      = (const float*)d_in[4];
  const float* g0      = (const float*)d_in[6];
  const float* be0     = (const float*)d_in[7];
  const float* W1      = (const float*)d_in[8];
  const float* g1      = (const float*)d_in[10];
  const float* be1     = (const float*)d_in[11];
  float* out = (float*)d_out;

  // workspace layout (bytes)
  char* ws = (char*)d_ws;
  unsigned short* X   = (unsigned short*)(ws);                       // ROWS*384 bf16 (reused for Y2)
  unsigned short* Y1  = (unsigned short*)(ws + 50331648);            // ROWS*256 bf16
  unsigned short* W0t = (unsigned short*)(ws + 50331648 + 33554432); // 384*256 bf16 (transposed)
  unsigned short* W1t = (unsigned short*)(ws + 50331648 + 33554432 + 196608);
  float* stats = (float*)(ws + 50331648 + 33554432 + 196608 + 131072); // 1024 f32 (two BN stat sets)
  float* scsh  = stats + 1024;                                        // 1024 f32 (two scale/shift sets)
  int*   idx   = (int*)(scsh + 1024);                                 // ROWS*3
  float* wgt   = (float*)(idx + ROWS * 3);                            // ROWS*3
  unsigned short* Y2 = X;  // x buffer free after gemm1

  hipMemsetAsync(stats, 0, 1024 * sizeof(float), stream);

  wt_kernel<<<(CIN * CO + 255) / 256, 256, 0, stream>>>(W0, W0t, CIN, CO);
  wt_kernel<<<(CO * CO + 255) / 256, 256, 0, stream>>>(W1, W1t, CO, CO);

  nn_kernel<<<BB * (NN / 32), 256, 0, stream>>>(xyz1, xyz2, idx, wgt);
  interp_kernel<<<ROWS / 2, 256, 0, stream>>>(points2, points1, idx, wgt, X);

  dim3 gg(ROWS / 128, 2);
  gemm_nt<<<gg, 256, 0, stream>>>(X, W0t, Y1, stats, CIN, CO);
  finalize_kernel<<<1, 256, 0, stream>>>(stats, g0, be0, scsh);
  apply_bf16<<<(size_t)ROWS * CO / (256 * 8), 256, 0, stream>>>(Y1, scsh);

  gemm_nt<<<gg, 256, 0, stream>>>(Y1, W1t, Y2, stats + 512, CO, CO);
  finalize_kernel<<<1, 256, 0, stream>>>(stats + 512, g1, be1, scsh + 512);
  apply_f32<<<(size_t)ROWS * CO / (256 * 8), 256, 0, stream>>>(Y2, scsh + 512, out);
}

// Round 3
// 175.532 us; speedup vs baseline: 1.5493x; 1.1547x over previous
//
#include <hip/hip_runtime.h>
#include <hip/hip_bf16.h>
#include <stdint.h>

#define BB 16
#define NN 4096
#define MM 1024
#define C1 128
#define C2 256
#define CIN 384
#define CO 256
#define ROWS (BB * NN)

typedef __attribute__((ext_vector_type(8))) short bf16x8;
typedef __attribute__((ext_vector_type(4))) float f32x4;

__device__ inline float u2f(uint32_t u) { union { uint32_t u; float f; } v; v.u = u; return v.f; }
__device__ inline uint32_t f2u(float f) { union { float f; uint32_t u; } v; v.f = f; return v.u; }
// round-to-nearest-even f32 -> bf16
__device__ inline unsigned short f2bf(float f) {
  uint32_t u = f2u(f);
  uint32_t r = u + 0x7fffu + ((u >> 16) & 1u);
  return (unsigned short)(r >> 16);
}
__device__ inline float bflo(uint32_t w) { return u2f(w << 16); }
__device__ inline float bfhi(uint32_t w) { return u2f(w & 0xffff0000u); }

// ---------------------------------------------------------------- three_nn
#define NN_INS(dd, jj_)                                        \
  {                                                            \
    bool c0 = (dd) < e0, c1 = (dd) < e1, c2 = (dd) < e2;       \
    e2 = c2 ? (c1 ? e1 : (dd)) : e2;                           \
    i2 = c2 ? (c1 ? i1 : (jj_)) : i2;                          \
    e1 = c1 ? (c0 ? e0 : (dd)) : e1;                           \
    i1 = c1 ? (c0 ? i0 : (jj_)) : i1;                          \
    e0 = c0 ? (dd) : e0;                                       \
    i0 = c0 ? (jj_) : i0;                                      \
  }

__global__ __launch_bounds__(256) void nn_kernel(const float* __restrict__ xyz1,
                                                 const float* __restrict__ xyz2,
                                                 int* __restrict__ idx,
                                                 float* __restrict__ wgt) {
  __shared__ float4 q[MM];  // 16 KB
  int b = blockIdx.x >> 7;                 // 128 blocks per batch (N/32)
  int qbase = (blockIdx.x & 127) << 5;     // 32 queries per block
  const float* x2 = xyz2 + (size_t)b * MM * 3;
  for (int j = threadIdx.x; j < MM; j += 256)
    q[j] = make_float4(x2[j * 3 + 0], x2[j * 3 + 1], x2[j * 3 + 2], 0.f);
  __syncthreads();
  int n = qbase + (threadIdx.x >> 3);
  int tq = threadIdx.x & 7;
  const float* p = xyz1 + ((size_t)b * NN + n) * 3;
  float px = p[0], py = p[1], pz = p[2];
  float e0 = 1e30f, e1 = 1e30f, e2 = 1e30f;
  int i0 = 0, i1 = 0, i2 = 0;
#pragma unroll 8
  for (int jj = 0; jj < MM / 8; ++jj) {
    int j = jj * 8 + tq;
    float4 qv = q[j];
    float dx = px - qv.x, dy = py - qv.y, dz = pz - qv.z;
    float d = dx * dx + dy * dy + dz * dz;
    NN_INS(d, j);
  }
#pragma unroll
  for (int mk = 1; mk <= 4; mk <<= 1) {
    float f0 = __shfl_xor(e0, mk), f1 = __shfl_xor(e1, mk), f2 = __shfl_xor(e2, mk);
    int j0 = __shfl_xor(i0, mk), j1 = __shfl_xor(i1, mk), j2 = __shfl_xor(i2, mk);
    NN_INS(f0, j0);
    NN_INS(f1, j1);
    NN_INS(f2, j2);
  }
  if (tq == 0) {
    float a0 = fmaxf(e0, 1e-10f), a1 = fmaxf(e1, 1e-10f), a2 = fmaxf(e2, 1e-10f);
    float v0 = 1.f / a0, v1 = 1.f / a1, v2 = 1.f / a2;
    float inv = 1.f / (v0 + v1 + v2);
    size_t base = ((size_t)b * NN + n) * 3;
    idx[base + 0] = i0; idx[base + 1] = i1; idx[base + 2] = i2;
    wgt[base + 0] = v0 * inv; wgt[base + 1] = v1 * inv; wgt[base + 2] = v2 * inv;
  }
}

// -------------------------------------------- interpolate + concat -> x bf16
__global__ __launch_bounds__(256) void interp_kernel(const float* __restrict__ points2,
                                                     const float* __restrict__ points1,
                                                     const int* __restrict__ idx,
                                                     const float* __restrict__ wgt,
                                                     unsigned short* __restrict__ X) {
  int row = blockIdx.x * 2 + (threadIdx.x >> 7);
  int t = threadIdx.x & 127;
  int b = row >> 12;  // N = 4096 rows per batch
  unsigned short* xr = X + (size_t)row * CIN;
  if (t < 64) {
    const int* id = idx + (size_t)row * 3;
    const float* w = wgt + (size_t)row * 3;
    const float* p2 = points2 + (size_t)b * MM * C2 + t * 4;
    float w0 = w[0], w1 = w[1], w2 = w[2];
    float4 a0 = *(const float4*)(p2 + (size_t)id[0] * C2);
    float4 a1 = *(const float4*)(p2 + (size_t)id[1] * C2);
    float4 a2 = *(const float4*)(p2 + (size_t)id[2] * C2);
    ushort4 o;
    o.x = f2bf(w0 * a0.x + w1 * a1.x + w2 * a2.x);
    o.y = f2bf(w0 * a0.y + w1 * a1.y + w2 * a2.y);
    o.z = f2bf(w0 * a0.z + w1 * a1.z + w2 * a2.z);
    o.w = f2bf(w0 * a0.w + w1 * a1.w + w2 * a2.w);
    *(ushort4*)(xr + t * 4) = o;
  } else if (t < 96) {
    int c = (t - 64) * 4;
    float4 a = *(const float4*)(points1 + (size_t)row * C1 + c);
    ushort4 o;
    o.x = f2bf(a.x); o.y = f2bf(a.y); o.z = f2bf(a.z); o.w = f2bf(a.w);
    *(ushort4*)(xr + C2 + c) = o;
  }
}

// ---------------------------- weight -> per-lane MFMA fragment stream (bf16)
// Layout (per panel p of 128 cols): 16B-unit u = (s*8 + f)*64 + lane holds
// W[k = s*32 + (lane>>4)*8 + e][n = p*128 + f*16 + (lane&15)], e = 0..7.
__global__ __launch_bounds__(256) void wt_stream(const float* __restrict__ W,
                                                 unsigned short* __restrict__ Ws,
                                                 int K) {
  int i = blockIdx.x * 256 + threadIdx.x;          // 16B-unit index
  int total = K * 32;                              // two panels, K*16 each
  if (i >= total) return;
  int p = i / (K * 16);
  int r = i - p * (K * 16);
  int s = r >> 9;
  int f = (r >> 6) & 7;
  int l = r & 63;
  int k0 = s * 32 + ((l >> 4) << 3);
  int n = (p << 7) + (f << 4) + (l & 15);
  unsigned short v[8];
#pragma unroll
  for (int e = 0; e < 8; ++e) v[e] = f2bf(W[(size_t)(k0 + e) * CO + n]);
  *(uint4*)(Ws + (size_t)i * 8) = *(uint4*)v;
}

// --------------------------------------------- streaming GEMM, B-in-LDS
// C[m][n] = sum_k A'[m][k] * W[k][n], A' = FUSE ? relu(A*sc+sh) : A.
// Block: 512 thr = 8 waves (4 row x 2 col), 256 rows x 128-col panel.
// No barriers in main loop; A streamed global->reg as MFMA fragments.
template <int K, bool FUSE>
__global__ __launch_bounds__(512) void gemm_stream(const unsigned short* __restrict__ A,
                                                   const unsigned short* __restrict__ Bs,
                                                   unsigned short* __restrict__ C,
                                                   float* __restrict__ stats,
                                                   const float* __restrict__ scsh) {
  constexpr int STEPS = K / 32;
  __shared__ unsigned short lB[K * 128];
  __shared__ float sdat[256];
  __shared__ float lsc[256], lsh[256];
  int tid = threadIdx.x, lane = tid & 63, wave = tid >> 6;
  int wr = wave >> 1, wc = wave & 1;
  int panel = blockIdx.x & 1, rt = blockIdx.x >> 1;
  int m0 = rt * 256;
  // prologue: copy B panel into LDS; stage BN scale/shift
  const uint4* src = (const uint4*)(Bs + (size_t)panel * K * 128);
  for (int u = tid; u < K * 16; u += 512) ((uint4*)lB)[u] = src[u];
  if (tid < 256) {
    sdat[tid] = 0.f;
    if (FUSE) { lsc[tid] = scsh[tid]; lsh[tid] = scsh[256 + tid]; }
  }
  __syncthreads();

  int arow = m0 + wr * 64 + (lane & 15);
  int kcol = (lane >> 4) * 8;
  const unsigned short* Abase = A + (size_t)arow * K + kcol;

  f32x4 acc[4][4] = {};
  uint4 pA[4], pB[4];
#pragma unroll
  for (int mf = 0; mf < 4; ++mf) pA[mf] = *(const uint4*)(Abase + (size_t)mf * 16 * K);
#pragma unroll
  for (int mf = 0; mf < 4; ++mf) pB[mf] = *(const uint4*)(Abase + (size_t)mf * 16 * K + 32);

#define CONV_FRAG(raw, sidx, dst)                                              \
  {                                                                            \
    if (!FUSE) {                                                               \
      union { uint4 u; bf16x8 h; } cv_; cv_.u = (raw); (dst) = cv_.h;          \
    } else {                                                                   \
      int kb_ = (sidx) * 32 + kcol;                                            \
      float4 c0_ = *(const float4*)&lsc[kb_], c1_ = *(const float4*)&lsc[kb_ + 4]; \
      float4 h0_ = *(const float4*)&lsh[kb_], h1_ = *(const float4*)&lsh[kb_ + 4]; \
      uint32_t rw_[4] = {(raw).x, (raw).y, (raw).z, (raw).w};                  \
      float scf_[8] = {c0_.x, c0_.y, c0_.z, c0_.w, c1_.x, c1_.y, c1_.z, c1_.w}; \
      float shf_[8] = {h0_.x, h0_.y, h0_.z, h0_.w, h1_.x, h1_.y, h1_.z, h1_.w}; \
      union { uint4 u; bf16x8 h; } cv_;                                        \
      uint32_t ow_[4];                                                         \
      _Pragma("unroll") for (int q_ = 0; q_ < 4; ++q_) {                       \
        float lo_ = fmaxf(bflo(rw_[q_]) * scf_[2 * q_] + shf_[2 * q_], 0.f);   \
        float hi_ = fmaxf(bfhi(rw_[q_]) * scf_[2 * q_ + 1] + shf_[2 * q_ + 1], 0.f); \
        ow_[q_] = (uint32_t)f2bf(lo_) | ((uint32_t)f2bf(hi_) << 16);           \
      }                                                                        \
      cv_.u.x = ow_[0]; cv_.u.y = ow_[1]; cv_.u.z = ow_[2]; cv_.u.w = ow_[3];  \
      (dst) = cv_.h;                                                           \
    }                                                                          \
  }

#define DO_STEP(pbuf, sidx)                                                    \
  {                                                                            \
    bf16x8 bfr[4];                                                             \
    _Pragma("unroll") for (int n2 = 0; n2 < 4; ++n2)                           \
      bfr[n2] = *(const bf16x8*)&lB[(((sidx) * 8 + wc * 4 + n2) * 64 + lane) * 8]; \
    bf16x8 af[4];                                                              \
    _Pragma("unroll") for (int mf = 0; mf < 4; ++mf) CONV_FRAG(pbuf[mf], sidx, af[mf]); \
    if ((sidx) + 2 < STEPS) {                                                  \
      _Pragma("unroll") for (int mf = 0; mf < 4; ++mf)                         \
        pbuf[mf] = *(const uint4*)(Abase + (size_t)mf * 16 * K + ((sidx) + 2) * 32); \
    }                                                                          \
    _Pragma("unroll") for (int mf = 0; mf < 4; ++mf)                           \
      _Pragma("unroll") for (int n2 = 0; n2 < 4; ++n2)                         \
        acc[mf][n2] = __builtin_amdgcn_mfma_f32_16x16x32_bf16(af[mf], bfr[n2], acc[mf][n2], 0, 0, 0); \
  }

  for (int s = 0; s < STEPS; s += 2) {
    DO_STEP(pA, s);
    DO_STEP(pB, s + 1);
  }
#undef DO_STEP
#undef CONV_FRAG

  // ---- C write (bf16, raw pre-BN values) ----
  int crow0 = m0 + wr * 64 + (lane >> 4) * 4;
  int ccol0 = panel * 128 + wc * 64 + (lane & 15);
#pragma unroll
  for (int mf = 0; mf < 4; ++mf)
#pragma unroll
    for (int n2 = 0; n2 < 4; ++n2) {
      size_t rb = (size_t)(crow0 + mf * 16);
      int cc = ccol0 + n2 * 16;
#pragma unroll
      for (int j = 0; j < 4; ++j)
        C[(rb + j) * CO + cc] = f2bf(acc[mf][n2][j]);
    }
  // ---- fused BN stats ----
  float s4[4] = {0.f, 0.f, 0.f, 0.f}, q4[4] = {0.f, 0.f, 0.f, 0.f};
#pragma unroll
  for (int mf = 0; mf < 4; ++mf)
#pragma unroll
    for (int n2 = 0; n2 < 4; ++n2)
#pragma unroll
      for (int j = 0; j < 4; ++j) {
        float v = acc[mf][n2][j];
        s4[n2] += v;
        q4[n2] += v * v;
      }
#pragma unroll
  for (int n2 = 0; n2 < 4; ++n2) {
    s4[n2] += __shfl_xor(s4[n2], 16);
    q4[n2] += __shfl_xor(q4[n2], 16);
    s4[n2] += __shfl_xor(s4[n2], 32);
    q4[n2] += __shfl_xor(q4[n2], 32);
  }
  if (lane < 16) {
#pragma unroll
    for (int n2 = 0; n2 < 4; ++n2) {
      int cl = wc * 64 + n2 * 16 + (lane & 15);
      atomicAdd(&sdat[cl], s4[n2]);
      atomicAdd(&sdat[128 + cl], q4[n2]);
    }
  }
  __syncthreads();
  if (tid < 128) {
    atomicAdd(&stats[panel * 128 + tid], sdat[tid]);
    atomicAdd(&stats[256 + panel * 128 + tid], sdat[128 + tid]);
  }
}

__global__ void finalize_kernel(const float* __restrict__ stats, const float* __restrict__ g,
                                const float* __restrict__ be, float* __restrict__ scsh) {
  int c = threadIdx.x;
  float mean = stats[c] * (1.f / ROWS);
  float var = stats[256 + c] * (1.f / ROWS) - mean * mean;
  float sc = g[c] * rsqrtf(var + 1e-3f);
  scsh[c] = sc;
  scsh[256 + c] = be[c] - mean * sc;
}

// ----------------------------------------- BN+ReLU apply, fp32 out
__global__ __launch_bounds__(256) void apply_f32(const unsigned short* __restrict__ Y,
                                                 const float* __restrict__ scsh,
                                                 float* __restrict__ out) {
  __shared__ float sc[256], sh[256];
  int t = threadIdx.x;
  sc[t] = scsh[t]; sh[t] = scsh[256 + t];
  __syncthreads();
  size_t base = ((size_t)blockIdx.x * 256 + t) * 8;
  int c0 = (int)(base & 255);
  uint4 v = *(const uint4*)(Y + base);
  uint32_t wv[4] = {v.x, v.y, v.z, v.w};
  float o[8];
#pragma unroll
  for (int q = 0; q < 4; ++q) {
    o[2 * q]     = fmaxf(bflo(wv[q]) * sc[c0 + 2 * q] + sh[c0 + 2 * q], 0.f);
    o[2 * q + 1] = fmaxf(bfhi(wv[q]) * sc[c0 + 2 * q + 1] + sh[c0 + 2 * q + 1], 0.f);
  }
  *(float4*)(out + base) = make_float4(o[0], o[1], o[2], o[3]);
  *(float4*)(out + base + 4) = make_float4(o[4], o[5], o[6], o[7]);
}

extern "C" void kernel_launch(void* const* d_in, const int* in_sizes, int n_in,
                              void* d_out, int out_size, void* d_ws, size_t ws_size,
                              hipStream_t stream) {
  const float* xyz1    = (const float*)d_in[0];
  const float* xyz2    = (const float*)d_in[1];
  const float* points1 = (const float*)d_in[2];
  const float* points2 = (const float*)d_in[3];
  const float* W0      = (const float*)d_in[4];
  const float* g0      = (const float*)d_in[6];
  const float* be0     = (const float*)d_in[7];
  const float* W1      = (const float*)d_in[8];
  const float* g1      = (const float*)d_in[10];
  const float* be1     = (const float*)d_in[11];
  float* out = (float*)d_out;

  // workspace layout (bytes)
  char* ws = (char*)d_ws;
  unsigned short* X   = (unsigned short*)(ws);                       // ROWS*384 bf16 (reused for Y2)
  unsigned short* Y1  = (unsigned short*)(ws + 50331648);            // ROWS*256 bf16
  unsigned short* W0s = (unsigned short*)(ws + 50331648 + 33554432); // 384*256 bf16 stream
  unsigned short* W1s = (unsigned short*)(ws + 50331648 + 33554432 + 196608);
  float* stats = (float*)(ws + 50331648 + 33554432 + 196608 + 131072); // 1024 f32
  float* scsh  = stats + 1024;                                        // 1024 f32
  int*   idx   = (int*)(scsh + 1024);                                 // ROWS*3
  float* wgt   = (float*)(idx + ROWS * 3);                            // ROWS*3
  unsigned short* Y2 = X;  // X buffer free after gemm1

  hipMemsetAsync(stats, 0, 1024 * sizeof(float), stream);

  wt_stream<<<(CIN * 32 + 255) / 256, 256, 0, stream>>>(W0, W0s, CIN);
  wt_stream<<<(CO * 32 + 255) / 256, 256, 0, stream>>>(W1, W1s, CO);

  nn_kernel<<<BB * (NN / 32), 256, 0, stream>>>(xyz1, xyz2, idx, wgt);
  interp_kernel<<<ROWS / 2, 256, 0, stream>>>(points2, points1, idx, wgt, X);

  gemm_stream<CIN, false><<<(ROWS / 256) * 2, 512, 0, stream>>>(X, W0s, Y1, stats, nullptr);
  finalize_kernel<<<1, 256, 0, stream>>>(stats, g0, be0, scsh);

  gemm_stream<CO, true><<<(ROWS / 256) * 2, 512, 0, stream>>>(Y1, W1s, Y2, stats + 512, scsh);
  finalize_kernel<<<1, 256, 0, stream>>>(stats + 512, g1, be1, scsh + 512);

  apply_f32<<<(size_t)ROWS * CO / (256 * 8), 256, 0, stream>>>(Y2, scsh + 512, out);
}

// Round 4
// 171.409 us; speedup vs baseline: 1.5866x; 1.0241x over previous
//
#include <hip/hip_runtime.h>
#include <hip/hip_bf16.h>
#include <stdint.h>

#define BB 16
#define NN 4096
#define MM 1024
#define C1 128
#define C2 256
#define CIN 384
#define CO 256
#define ROWS (BB * NN)

typedef __attribute__((ext_vector_type(8))) short bf16x8;
typedef __attribute__((ext_vector_type(4))) float f32x4;

__device__ inline float u2f(uint32_t u) { union { uint32_t u; float f; } v; v.u = u; return v.f; }
__device__ inline uint32_t f2u(float f) { union { float f; uint32_t u; } v; v.f = f; return v.u; }
// round-to-nearest-even f32 -> bf16
__device__ inline unsigned short f2bf(float f) {
  uint32_t u = f2u(f);
  uint32_t r = u + 0x7fffu + ((u >> 16) & 1u);
  return (unsigned short)(r >> 16);
}
__device__ inline float bflo(uint32_t w) { return u2f(w << 16); }
__device__ inline float bfhi(uint32_t w) { return u2f(w & 0xffff0000u); }

// ---------------------------------------------------------------- three_nn
#define NN_INS(dd, jj_)                                        \
  {                                                            \
    bool c0 = (dd) < e0, c1 = (dd) < e1, c2 = (dd) < e2;       \
    e2 = c2 ? (c1 ? e1 : (dd)) : e2;                           \
    i2 = c2 ? (c1 ? i1 : (jj_)) : i2;                          \
    e1 = c1 ? (c0 ? e0 : (dd)) : e1;                           \
    i1 = c1 ? (c0 ? i0 : (jj_)) : i1;                          \
    e0 = c0 ? (dd) : e0;                                       \
    i0 = c0 ? (jj_) : i0;                                      \
  }

__global__ __launch_bounds__(256) void nn_kernel(const float* __restrict__ xyz1,
                                                 const float* __restrict__ xyz2,
                                                 int* __restrict__ idx,
                                                 float* __restrict__ wgt) {
  __shared__ float4 q[MM];  // 16 KB
  int b = blockIdx.x >> 7;                 // 128 blocks per batch (N/32)
  int qbase = (blockIdx.x & 127) << 5;     // 32 queries per block
  const float* x2 = xyz2 + (size_t)b * MM * 3;
  for (int j = threadIdx.x; j < MM; j += 256)
    q[j] = make_float4(x2[j * 3 + 0], x2[j * 3 + 1], x2[j * 3 + 2], 0.f);
  __syncthreads();
  int n = qbase + (threadIdx.x >> 3);
  int tq = threadIdx.x & 7;
  const float* p = xyz1 + ((size_t)b * NN + n) * 3;
  float px = p[0], py = p[1], pz = p[2];
  float e0 = 1e30f, e1 = 1e30f, e2 = 1e30f;
  int i0 = 0, i1 = 0, i2 = 0;
#pragma unroll 8
  for (int jj = 0; jj < MM / 8; ++jj) {
    int j = jj * 8 + tq;
    float4 qv = q[j];
    float dx = px - qv.x, dy = py - qv.y, dz = pz - qv.z;
    float d = dx * dx + dy * dy + dz * dz;
    NN_INS(d, j);
  }
#pragma unroll
  for (int mk = 1; mk <= 4; mk <<= 1) {
    float f0 = __shfl_xor(e0, mk), f1 = __shfl_xor(e1, mk), f2 = __shfl_xor(e2, mk);
    int j0 = __shfl_xor(i0, mk), j1 = __shfl_xor(i1, mk), j2 = __shfl_xor(i2, mk);
    NN_INS(f0, j0);
    NN_INS(f1, j1);
    NN_INS(f2, j2);
  }
  if (tq == 0) {
    float a0 = fmaxf(e0, 1e-10f), a1 = fmaxf(e1, 1e-10f), a2 = fmaxf(e2, 1e-10f);
    float v0 = 1.f / a0, v1 = 1.f / a1, v2 = 1.f / a2;
    float inv = 1.f / (v0 + v1 + v2);
    size_t base = ((size_t)b * NN + n) * 3;
    idx[base + 0] = i0; idx[base + 1] = i1; idx[base + 2] = i2;
    wgt[base + 0] = v0 * inv; wgt[base + 1] = v1 * inv; wgt[base + 2] = v2 * inv;
  }
}

// -------------------------------------------- interpolate + concat -> x bf16
__global__ __launch_bounds__(256) void interp_kernel(const float* __restrict__ points2,
                                                     const float* __restrict__ points1,
                                                     const int* __restrict__ idx,
                                                     const float* __restrict__ wgt,
                                                     unsigned short* __restrict__ X) {
  int row = blockIdx.x * 2 + (threadIdx.x >> 7);
  int t = threadIdx.x & 127;
  int b = row >> 12;  // N = 4096 rows per batch
  unsigned short* xr = X + (size_t)row * CIN;
  if (t < 64) {
    const int* id = idx + (size_t)row * 3;
    const float* w = wgt + (size_t)row * 3;
    const float* p2 = points2 + (size_t)b * MM * C2 + t * 4;
    float w0 = w[0], w1 = w[1], w2 = w[2];
    float4 a0 = *(const float4*)(p2 + (size_t)id[0] * C2);
    float4 a1 = *(const float4*)(p2 + (size_t)id[1] * C2);
    float4 a2 = *(const float4*)(p2 + (size_t)id[2] * C2);
    ushort4 o;
    o.x = f2bf(w0 * a0.x + w1 * a1.x + w2 * a2.x);
    o.y = f2bf(w0 * a0.y + w1 * a1.y + w2 * a2.y);
    o.z = f2bf(w0 * a0.z + w1 * a1.z + w2 * a2.z);
    o.w = f2bf(w0 * a0.w + w1 * a1.w + w2 * a2.w);
    *(ushort4*)(xr + t * 4) = o;
  } else if (t < 96) {
    int c = (t - 64) * 4;
    float4 a = *(const float4*)(points1 + (size_t)row * C1 + c);
    ushort4 o;
    o.x = f2bf(a.x); o.y = f2bf(a.y); o.z = f2bf(a.z); o.w = f2bf(a.w);
    *(ushort4*)(xr + C2 + c) = o;
  }
}

// ---------------------------- weight -> per-lane MFMA fragment stream (bf16)
// 64-col panels (4 of them). Unit u = p*(K*8) + (s*4 + f)*64 + l  holds
// W[k = s*32 + (l>>4)*8 + e][n = p*64 + f*16 + (l&15)], e = 0..7.
// Also zeroes this layer's 512-float stats slice (block 0).
__global__ __launch_bounds__(256) void wt_stream(const float* __restrict__ W,
                                                 unsigned short* __restrict__ Ws,
                                                 int K, float* __restrict__ stats) {
  int t = threadIdx.x;
  if (blockIdx.x == 0) { stats[t] = 0.f; stats[256 + t] = 0.f; }
  int i = blockIdx.x * 256 + t;  // 16B-unit index
  int total = K * 32;
  if (i >= total) return;
  int p = i / (K * 8);
  int r = i - p * (K * 8);
  int s = r >> 8;
  int f = (r >> 6) & 3;
  int l = r & 63;
  int k0 = s * 32 + ((l >> 4) << 3);
  int n = (p << 6) + (f << 4) + (l & 15);
  unsigned short v[8];
#pragma unroll
  for (int e = 0; e < 8; ++e) v[e] = f2bf(W[(size_t)(k0 + e) * CO + n]);
  *(uint4*)(Ws + (size_t)i * 8) = *(uint4*)v;
}

// --------------------------------------------- streaming GEMM, B-in-LDS
// C[m][n] = sum_k A'[m][k] * W[k][n], A' = FUSE ? relu(A*sc+sh) : A.
// Block: 256 thr = 4 waves (row-stacked), tile = 256 rows x 64-col panel.
// No barriers in main loop; A global->reg as MFMA fragments, 4-deep prefetch.
template <int K, bool FUSE>
__global__ __launch_bounds__(256, 3) void gemm_stream(const unsigned short* __restrict__ A,
                                                      const unsigned short* __restrict__ Bs,
                                                      unsigned short* __restrict__ C,
                                                      float* __restrict__ stats,
                                                      const float* __restrict__ scsh) {
  constexpr int STEPS = K / 32;
  __shared__ unsigned short lB[K * 64];   // 48 KB (K=384) / 32 KB (K=256)
  __shared__ float sdat[128];             // 64 col sums + 64 col sumsq
  __shared__ float lscsh[512];            // BN scale[256] + shift[256]
  int tid = threadIdx.x, lane = tid & 63, w = tid >> 6;
  // XCD-chunked bijective swizzle (1024 blocks, 8 XCDs): panel-blocks of one
  // row-tile land on one XCD -> A re-reads are L2 hits.
  int wg = ((blockIdx.x & 7) << 7) | (blockIdx.x >> 3);
  int panel = wg & 3, rt = wg >> 2;
  int m0 = rt * 256;
  // prologue: copy B panel to LDS; stage BN scale/shift; zero sdat
  const uint4* src = (const uint4*)(Bs + (size_t)panel * K * 64);
  for (int u = tid; u < K * 8; u += 256) ((uint4*)lB)[u] = src[u];
  if (tid < 128) sdat[tid] = 0.f;
  if (FUSE) { lscsh[tid] = scsh[tid]; lscsh[256 + tid] = scsh[256 + tid]; }
  __syncthreads();

  int arow = m0 + w * 64 + (lane & 15);
  int kcol = (lane >> 4) * 8;
  const unsigned short* Abase = A + (size_t)arow * K + kcol;

  f32x4 acc[4][4] = {};
  uint4 pA[4], pB[4], pC4[4], pD[4];
#pragma unroll
  for (int mf = 0; mf < 4; ++mf) {
    pA[mf]  = *(const uint4*)(Abase + (size_t)mf * 16 * K);
    pB[mf]  = *(const uint4*)(Abase + (size_t)mf * 16 * K + 32);
    pC4[mf] = *(const uint4*)(Abase + (size_t)mf * 16 * K + 64);
    pD[mf]  = *(const uint4*)(Abase + (size_t)mf * 16 * K + 96);
  }

#define CONV_FRAG(raw, sidx, dst)                                              \
  {                                                                            \
    if (!FUSE) {                                                               \
      union { uint4 u; bf16x8 h; } cv_; cv_.u = (raw); (dst) = cv_.h;          \
    } else {                                                                   \
      int kb_ = (sidx) * 32 + kcol;                                            \
      uint32_t rw_[4] = {(raw).x, (raw).y, (raw).z, (raw).w};                  \
      union { uint4 u; bf16x8 h; } cv_;                                        \
      uint32_t ow_[4];                                                         \
      _Pragma("unroll") for (int q_ = 0; q_ < 4; ++q_) {                       \
        float lo_ = fmaxf(bflo(rw_[q_]) * lscsh[kb_ + 2 * q_] + lscsh[256 + kb_ + 2 * q_], 0.f); \
        float hi_ = fmaxf(bfhi(rw_[q_]) * lscsh[kb_ + 2 * q_ + 1] + lscsh[256 + kb_ + 2 * q_ + 1], 0.f); \
        ow_[q_] = (uint32_t)f2bf(lo_) | ((uint32_t)f2bf(hi_) << 16);           \
      }                                                                        \
      cv_.u.x = ow_[0]; cv_.u.y = ow_[1]; cv_.u.z = ow_[2]; cv_.u.w = ow_[3];  \
      (dst) = cv_.h;                                                           \
    }                                                                          \
  }

#define DO_STEP(pbuf, sidx)                                                    \
  {                                                                            \
    bf16x8 bfr[4];                                                             \
    _Pragma("unroll") for (int f = 0; f < 4; ++f)                              \
      bfr[f] = *(const bf16x8*)&lB[(((sidx) * 4 + f) * 64 + lane) * 8];        \
    bf16x8 af[4];                                                              \
    _Pragma("unroll") for (int mf = 0; mf < 4; ++mf) CONV_FRAG(pbuf[mf], sidx, af[mf]); \
    if ((sidx) + 4 < STEPS) {                                                  \
      _Pragma("unroll") for (int mf = 0; mf < 4; ++mf)                         \
        pbuf[mf] = *(const uint4*)(Abase + (size_t)mf * 16 * K + ((sidx) + 4) * 32); \
    }                                                                          \
    _Pragma("unroll") for (int mf = 0; mf < 4; ++mf)                           \
      _Pragma("unroll") for (int f = 0; f < 4; ++f)                            \
        acc[mf][f] = __builtin_amdgcn_mfma_f32_16x16x32_bf16(af[mf], bfr[f], acc[mf][f], 0, 0, 0); \
  }

#pragma unroll
  for (int s = 0; s < STEPS; s += 4) {
    DO_STEP(pA, s);
    DO_STEP(pB, s + 1);
    DO_STEP(pC4, s + 2);
    DO_STEP(pD, s + 3);
  }
#undef DO_STEP
#undef CONV_FRAG

  // ---- C write (bf16, raw pre-BN values) ----
  int crow0 = m0 + w * 64 + (lane >> 4) * 4;
  int ccol0 = panel * 64 + (lane & 15);
#pragma unroll
  for (int mf = 0; mf < 4; ++mf)
#pragma unroll
    for (int f = 0; f < 4; ++f) {
      size_t rb = (size_t)(crow0 + mf * 16);
      int cc = ccol0 + f * 16;
#pragma unroll
      for (int j = 0; j < 4; ++j)
        C[(rb + j) * CO + cc] = f2bf(acc[mf][f][j]);
    }
  // ---- fused BN stats ----
  float s4[4] = {0.f, 0.f, 0.f, 0.f}, q4[4] = {0.f, 0.f, 0.f, 0.f};
#pragma unroll
  for (int mf = 0; mf < 4; ++mf)
#pragma unroll
    for (int f = 0; f < 4; ++f)
#pragma unroll
      for (int j = 0; j < 4; ++j) {
        float v = acc[mf][f][j];
        s4[f] += v;
        q4[f] += v * v;
      }
#pragma unroll
  for (int f = 0; f < 4; ++f) {
    s4[f] += __shfl_xor(s4[f], 16);
    q4[f] += __shfl_xor(q4[f], 16);
    s4[f] += __shfl_xor(s4[f], 32);
    q4[f] += __shfl_xor(q4[f], 32);
  }
  if (lane < 16) {
#pragma unroll
    for (int f = 0; f < 4; ++f) {
      int cl = f * 16 + lane;
      atomicAdd(&sdat[cl], s4[f]);
      atomicAdd(&sdat[64 + cl], q4[f]);
    }
  }
  __syncthreads();
  if (tid < 64) {
    atomicAdd(&stats[panel * 64 + tid], sdat[tid]);
    atomicAdd(&stats[256 + panel * 64 + tid], sdat[64 + tid]);
  }
}

__global__ void finalize_kernel(const float* __restrict__ stats, const float* __restrict__ g,
                                const float* __restrict__ be, float* __restrict__ scsh) {
  int c = threadIdx.x;
  float mean = stats[c] * (1.f / ROWS);
  float var = stats[256 + c] * (1.f / ROWS) - mean * mean;
  float sc = g[c] * rsqrtf(var + 1e-3f);
  scsh[c] = sc;
  scsh[256 + c] = be[c] - mean * sc;
}

// ----------------------------------------- BN+ReLU apply, fp32 out
__global__ __launch_bounds__(256) void apply_f32(const unsigned short* __restrict__ Y,
                                                 const float* __restrict__ scsh,
                                                 float* __restrict__ out) {
  __shared__ float sc[256], sh[256];
  int t = threadIdx.x;
  sc[t] = scsh[t]; sh[t] = scsh[256 + t];
  __syncthreads();
  size_t base = ((size_t)blockIdx.x * 256 + t) * 8;
  int c0 = (int)(base & 255);
  uint4 v = *(const uint4*)(Y + base);
  uint32_t wv[4] = {v.x, v.y, v.z, v.w};
  float o[8];
#pragma unroll
  for (int q = 0; q < 4; ++q) {
    o[2 * q]     = fmaxf(bflo(wv[q]) * sc[c0 + 2 * q] + sh[c0 + 2 * q], 0.f);
    o[2 * q + 1] = fmaxf(bfhi(wv[q]) * sc[c0 + 2 * q + 1] + sh[c0 + 2 * q + 1], 0.f);
  }
  *(float4*)(out + base) = make_float4(o[0], o[1], o[2], o[3]);
  *(float4*)(out + base + 4) = make_float4(o[4], o[5], o[6], o[7]);
}

extern "C" void kernel_launch(void* const* d_in, const int* in_sizes, int n_in,
                              void* d_out, int out_size, void* d_ws, size_t ws_size,
                              hipStream_t stream) {
  const float* xyz1    = (const float*)d_in[0];
  const float* xyz2    = (const float*)d_in[1];
  const float* points1 = (const float*)d_in[2];
  const float* points2 = (const float*)d_in[3];
  const float* W0      = (const float*)d_in[4];
  const float* g0      = (const float*)d_in[6];
  const float* be0     = (const float*)d_in[7];
  const float* W1      = (const float*)d_in[8];
  const float* g1      = (const float*)d_in[10];
  const float* be1     = (const float*)d_in[11];
  float* out = (float*)d_out;

  // workspace layout (bytes)
  char* ws = (char*)d_ws;
  unsigned short* X   = (unsigned short*)(ws);                       // ROWS*384 bf16 (reused for Y2)
  unsigned short* Y1  = (unsigned short*)(ws + 50331648);            // ROWS*256 bf16
  unsigned short* W0s = (unsigned short*)(ws + 50331648 + 33554432); // 384*256 bf16 stream
  unsigned short* W1s = (unsigned short*)(ws + 50331648 + 33554432 + 196608);
  float* stats = (float*)(ws + 50331648 + 33554432 + 196608 + 131072); // 1024 f32
  float* scsh  = stats + 1024;                                        // 1024 f32
  int*   idx   = (int*)(scsh + 1024);                                 // ROWS*3
  float* wgt   = (float*)(idx + ROWS * 3);                            // ROWS*3
  unsigned short* Y2 = X;  // X buffer free after gemm1

  wt_stream<<<(CIN * 32 + 255) / 256, 256, 0, stream>>>(W0, W0s, CIN, stats);
  wt_stream<<<(CO * 32 + 255) / 256, 256, 0, stream>>>(W1, W1s, CO, stats + 512);

  nn_kernel<<<BB * (NN / 32), 256, 0, stream>>>(xyz1, xyz2, idx, wgt);
  interp_kernel<<<ROWS / 2, 256, 0, stream>>>(points2, points1, idx, wgt, X);

  gemm_stream<CIN, false><<<(ROWS / 256) * 4, 256, 0, stream>>>(X, W0s, Y1, stats, nullptr);
  finalize_kernel<<<1, 256, 0, stream>>>(stats, g0, be0, scsh);

  gemm_stream<CO, true><<<(ROWS / 256) * 4, 256, 0, stream>>>(Y1, W1s, Y2, stats + 512, scsh);
  finalize_kernel<<<1, 256, 0, stream>>>(stats + 512, g1, be1, scsh + 512);

  apply_f32<<<(size_t)ROWS * CO / (256 * 8), 256, 0, stream>>>(Y2, scsh + 512, out);
}